// Round 7
// baseline (349.333 us; speedup 1.0000x reference)
//
#include <hip/hip_runtime.h>

// StockLSTM R20 = R18's spill-free 2-tile/wave structure + 2 blocks/CU.
//  Allocator law (R17/R18/R19): arch-VGPR cap = (512/wpe_min)/2 -> (4,4)=64,
//  (2,2)=128. R18's 8-wave 2-tile kernel = 88 arch VGPR: fits the 128 cap
//  AND the <=128/wave needed for 4 waves/EU runtime. R18 only missed 2
//  blocks/CU because MT=16 -> grid 256 = 1 block/CU. R19 proved the HW
//  co-schedules 2 blocks (occ 19.6%) when grid=512.
//  R20: MT=8, grid=512, waves_per_eu(2) MIN-ONLY (256 budget: no spill; no
//  max cap: HW free to run 4 waves/EU = two independent barrier domains/CU,
//  block A's trans-back overlaps block B's LDS/MFMA-front).
//  Batch-8 fills 16 MFMA cols by broadcast-read dup (lanes b8/b8+8 read the
//  same LDS address - free). Lane half sel owns ONE layer's cells for its 2
//  units (sel0->L1, sel1->L2): 2 cell_updates/thread, per-CU VALU identical
//  to R13, per-thread math bit-identical. Bias = per-lane post-add (8 regs).
//  SENTINELS: VGPR <=128 & WRITE_SIZE ~400 KB & Occupancy ~50%.

#define TT   256
#define II   5
#define HH   64
#define OO   25
#define MT   8
#define NTHR 512
#define XP   520        // x chunk row stride (ushorts): 64*8 + 8 skew
#define HSZ  512        // h parity block: [j>>3][b8][j&7] = 512 shorts
#define HF   65

typedef __attribute__((ext_vector_type(8))) short  short8;
typedef __attribute__((ext_vector_type(4))) float  floatx4;

#define MFMA(a, b, c) __builtin_amdgcn_mfma_f32_16x16x32_bf16(a, b, c, 0, 0, 0)

__device__ __forceinline__ float frcp(float x) { return __builtin_amdgcn_rcpf(x); }
__device__ __forceinline__ float fexp2(float x) { return __builtin_amdgcn_exp2f(x); }
__device__ __forceinline__ unsigned short bf16_rne(float f) {
    unsigned int u = __builtin_bit_cast(unsigned int, f);
    u += 0x7FFFu + ((u >> 16) & 1u);
    return (unsigned short)(u >> 16);
}
// gates arrive PRE-SCALED: g0,g1,g3 = -log2e*z ; g2 = +2log2e*z
__device__ __forceinline__ float cell_update(const floatx4& g, float& c) {
    const float gi = frcp(1.f + fexp2(g[0]));
    const float gf = frcp(1.f + fexp2(g[1]));
    const float gz = fmaf(-2.f, frcp(1.f + fexp2(g[2])), 1.f);
    const float go = frcp(1.f + fexp2(g[3]));
    c = fmaf(gf, c, gi * gz);
    const float tc = fmaf(-2.f, frcp(1.f + fexp2(c * 2.885390082f)), 1.f);
    return go * tc;
}

__global__ __attribute__((amdgpu_flat_work_group_size(512, 512),
                          amdgpu_waves_per_eu(2)))
void lstm_mfma16(const float* __restrict__ x,
                 const float* __restrict__ Wih0, const float* __restrict__ Whh0,
                 const float* __restrict__ bih0, const float* __restrict__ bhh0,
                 const float* __restrict__ Wih1, const float* __restrict__ Whh1,
                 const float* __restrict__ bih1, const float* __restrict__ bhh1,
                 const float* __restrict__ Wfc,  const float* __restrict__ bfc,
                 float* __restrict__ out)
{
    __shared__ __align__(16) unsigned short xhi[MT * XP];     // 8.3 KB
    __shared__ __align__(16) unsigned short h1hi[2 * HSZ];    // 2 KB
    __shared__ __align__(16) unsigned short h2hi[2 * HSZ];    // 2 KB
    __shared__ __align__(16) float          h2f[MT * HF];     // 2.1 KB

    const int tid   = threadIdx.x;
    const int w     = tid >> 6;          // wave 0..7: owns tiles 2w, 2w+1
    const int lane  = tid & 63;
    const int b8    = lane & 7;          // batch col (8 real; cols 8-15 dup)
    const int q     = lane >> 4;         // C row-quad / unit offset in tile
    const bool isl2 = ((lane >> 3) & 1) != 0;  // 0: own L1 cells, 1: own L2
    // lane's units: j_s = 8w + 4s + q (s=0,1). h layout [j>>3][b8][j&7]:
    const int hw_base = w * 64 + b8 * 8 + q;   // + 4*s
    const int ro8     = (q * 8 + b8) * 8;      // B-frag read (b8/b8+8 bcast)

    // ---------------- weights (bf16), nonlinearity scale folded in ----------------
    short8 A1h[2][2];   // [tile][k-chunk] Whh0
    short8 A2h[2][4];   // [tile][k-chunk] 0,1: Wih1 (h1); 2,3: Whh1 (h2)
    short8 Axwh[2];     // [tile] Wih0: k<II valid, rest exact zero
    {
        const int rr = lane & 15;
        const float sc = ((rr & 3) == 2) ? 2.885390082f : -1.442695041f;
        #pragma unroll
        for (int s = 0; s < 2; ++s) {
            const int g = (rr & 3) * 64 + 8 * w + 4 * s + (rr >> 2);
            #pragma unroll
            for (int c = 0; c < 2; ++c)
                #pragma unroll
                for (int jj = 0; jj < 8; ++jj)
                    A1h[s][c][jj] = (short)bf16_rne(sc * Whh0[g * HH + c * 32 + q * 8 + jj]);
            #pragma unroll
            for (int c = 0; c < 4; ++c)
                #pragma unroll
                for (int jj = 0; jj < 8; ++jj) {
                    const int k = c * 32 + q * 8 + jj;
                    float wv = (k < HH) ? Wih1[g * HH + k] : Whh1[g * HH + (k - HH)];
                    A2h[s][c][jj] = (short)bf16_rne(sc * wv);
                }
            #pragma unroll
            for (int jj = 0; jj < 8; ++jj) {
                const int k = q * 8 + jj;
                Axwh[s][jj] = (k < II) ? (short)bf16_rne(sc * Wih0[g * II + k]) : (short)0;
            }
        }
    }
    // per-lane bias for the layer THIS lane owns (post-added): 8 regs
    float biasm[2][4];
    #pragma unroll
    for (int s = 0; s < 2; ++s) {
        const int jj = 8 * w + 4 * s + q;
        #pragma unroll
        for (int r = 0; r < 4; ++r) {
            const int g = r * 64 + jj;
            const float sc = (r == 2) ? 2.885390082f : -1.442695041f;
            biasm[s][r] = isl2 ? sc * (bih1[g] + bhh1[g])
                               : sc * (bih0[g] + bhh0[g]);
        }
    }

    // ---------------- zero LDS ----------------
    for (int i = tid; i < MT * XP / 2; i += NTHR)
        ((unsigned int*)xhi)[i] = 0u;
    if (tid < HSZ) {                             // HSZ uints = 2*HSZ shorts
        ((unsigned int*)h1hi)[tid] = 0u;
        ((unsigned int*)h2hi)[tid] = 0u;
    }
    float cs0 = 0.f, cs1 = 0.f;                  // lane's 2 cell states
    __syncthreads();

    const int blockBase = blockIdx.x * MT;

    auto refill_x = [&](int t0) {
        const int rb = tid >> 6, dt = tid & 63;  // 8 rows x 64 t = 512 thr
        const float* src = x + ((size_t)(blockBase + rb) * TT + t0 + dt) * II;
        unsigned short* ph = xhi + rb * XP + dt * 8;
        #pragma unroll
        for (int ii = 0; ii < II; ++ii)
            ph[ii] = bf16_rne(src[ii]);
    };

    // per-lane h write pointers (parity + layer baked in; +4 for tile s=1):
    //  even intervals (WP=0,RP=1): sel0 writes h1[1], sel1 writes h2[0]
    //  odd  intervals (WP=1,RP=0): sel0 writes h1[0], sel1 writes h2[1]
    unsigned short* const hpE = (isl2 ? h2hi + 0 * HSZ : h1hi + 1 * HSZ) + hw_base;
    unsigned short* const hpO = (isl2 ? h2hi + 1 * HSZ : h1hi + 0 * HSZ) + hw_base;

    // ================= prologue: L1(0) =================
    refill_x(0);
    __syncthreads();
    {
        short8 Bxh = *(const short8*)(xhi + b8 * XP);       // dt = 0
        const floatx4 z4 = {0.f, 0.f, 0.f, 0.f};
        floatx4 a1t0 = MFMA(Axwh[0], Bxh, z4);
        floatx4 a1t1 = MFMA(Axwh[1], Bxh, z4);
        if (!isl2) {
            floatx4 g0, g1;
            #pragma unroll
            for (int r = 0; r < 4; ++r) { g0[r] = a1t0[r] + biasm[0][r];
                                          g1[r] = a1t1[r] + biasm[1][r]; }
            const float h0 = cell_update(g0, cs0);
            h1hi[0 * HSZ + hw_base + 0] = bf16_rne(h0);     // parity 0, s=0
            const float h1v = cell_update(g1, cs1);
            h1hi[0 * HSZ + hw_base + 4] = bf16_rne(h1v);    // parity 0, s=1
        }
    }
    __syncthreads();

    // x read pointer: STEP(i) reads dt=(i+1)&63; starts at dt=1.
    const unsigned short* xptr = xhi + b8 * XP + 8;

    // ================= merged main loop, unrolled by 2 =================
    // 14 MFMA/wave (2 tiles), then each lane finishes its OWN layer's 2 cells.
#define STEP_BODY(WP, RP, HP)                                                 \
    {                                                                         \
        short8 H1h0 = *(const short8*)(h1hi + (WP) * HSZ + ro8);              \
        short8 H1h1 = *(const short8*)(h1hi + (WP) * HSZ + 256 + ro8);        \
        short8 H2h0 = *(const short8*)(h2hi + (RP) * HSZ + ro8);              \
        short8 H2h1 = *(const short8*)(h2hi + (RP) * HSZ + 256 + ro8);        \
        short8 Bxh  = *(const short8*)(xptr);                                 \
        xptr += 8;                                                            \
        const floatx4 z4 = {0.f, 0.f, 0.f, 0.f};                              \
        floatx4 a2t0 = MFMA(A2h[0][0], H1h0, z4);                             \
        floatx4 a2t1 = MFMA(A2h[1][0], H1h0, z4);                             \
        a2t0 = MFMA(A2h[0][1], H1h1, a2t0);                                   \
        a2t1 = MFMA(A2h[1][1], H1h1, a2t1);                                   \
        a2t0 = MFMA(A2h[0][2], H2h0, a2t0);                                   \
        a2t1 = MFMA(A2h[1][2], H2h0, a2t1);                                   \
        a2t0 = MFMA(A2h[0][3], H2h1, a2t0);                                   \
        a2t1 = MFMA(A2h[1][3], H2h1, a2t1);                                   \
        floatx4 a1t0 = MFMA(Axwh[0], Bxh, z4);                                \
        floatx4 a1t1 = MFMA(Axwh[1], Bxh, z4);                                \
        a1t0 = MFMA(A1h[0][0], H1h0, a1t0);                                   \
        a1t1 = MFMA(A1h[1][0], H1h0, a1t1);                                   \
        a1t0 = MFMA(A1h[0][1], H1h1, a1t0);                                   \
        a1t1 = MFMA(A1h[1][1], H1h1, a1t1);                                   \
        floatx4 g0, g1;                                                       \
        _Pragma("unroll")                                                     \
        for (int r = 0; r < 4; ++r) {                                         \
            g0[r] = (isl2 ? a2t0[r] : a1t0[r]) + biasm[0][r];                 \
            g1[r] = (isl2 ? a2t1[r] : a1t1[r]) + biasm[1][r];                 \
        }                                                                     \
        {                                                                     \
            const float h = cell_update(g0, cs0);                             \
            (HP)[0] = bf16_rne(h);                                            \
        }                                                                     \
        {                                                                     \
            const float h = cell_update(g1, cs1);                             \
            (HP)[4] = bf16_rne(h);                                            \
        }                                                                     \
        __syncthreads();                                                      \
    }

    for (int i = 0; i < 254; i += 2) {
        STEP_BODY(0, 1, hpE)                 // interval i   (even)
        if (((i + 2) & 63) == 0) {           // refill before interval i+1
            refill_x(i + 2);
            xptr = xhi + b8 * XP;            //   next read is dt = 0
            __syncthreads();
        }
        STEP_BODY(1, 0, hpO)                 // interval i+1 (odd)
    }
    STEP_BODY(0, 1, hpE)                     // interval 254
#undef STEP_BODY

    // ================= epilogue: L2(255) =================
    {
        const floatx4 z4 = {0.f, 0.f, 0.f, 0.f};
        short8 H1h0 = *(const short8*)(h1hi + 1 * HSZ + ro8);
        short8 H1h1 = *(const short8*)(h1hi + 1 * HSZ + 256 + ro8);
        short8 H2h0 = *(const short8*)(h2hi + 0 * HSZ + ro8);
        short8 H2h1 = *(const short8*)(h2hi + 0 * HSZ + 256 + ro8);
        floatx4 a2t0 = MFMA(A2h[0][0], H1h0, z4);
        floatx4 a2t1 = MFMA(A2h[1][0], H1h0, z4);
        a2t0 = MFMA(A2h[0][1], H1h1, a2t0);
        a2t1 = MFMA(A2h[1][1], H1h1, a2t1);
        a2t0 = MFMA(A2h[0][2], H2h0, a2t0);
        a2t1 = MFMA(A2h[1][2], H2h0, a2t1);
        a2t0 = MFMA(A2h[0][3], H2h1, a2t0);
        a2t1 = MFMA(A2h[1][3], H2h1, a2t1);
        if (isl2) {
            floatx4 g0, g1;
            #pragma unroll
            for (int r = 0; r < 4; ++r) { g0[r] = a2t0[r] + biasm[0][r];
                                          g1[r] = a2t1[r] + biasm[1][r]; }
            const float h0 = cell_update(g0, cs0);
            h2f[b8 * HF + 8 * w + q] = h0;
            const float h1v = cell_update(g1, cs1);
            h2f[b8 * HF + 8 * w + 4 + q] = h1v;
        }
    }
    __syncthreads();

    // ================= FC epilogue =================
    if (tid < MT * OO) {
        const int bb = tid / OO, o = tid - bb * OO;
        float acc = bfc[o];
        const float* wr = Wfc + o * HH;
        const float* hr = h2f + bb * HF;
        #pragma unroll
        for (int j = 0; j < HH; ++j) acc += wr[j] * hr[j];
        out[((size_t)blockIdx.x * MT + bb) * OO + o] = acc;
    }
}

extern "C" void kernel_launch(void* const* d_in, const int* in_sizes, int n_in,
                              void* d_out, int out_size, void* d_ws, size_t ws_size,
                              hipStream_t stream) {
    const float* x    = (const float*)d_in[0];
    const float* Wih0 = (const float*)d_in[1];
    const float* Whh0 = (const float*)d_in[2];
    const float* bih0 = (const float*)d_in[3];
    const float* bhh0 = (const float*)d_in[4];
    const float* Wih1 = (const float*)d_in[5];
    const float* Whh1 = (const float*)d_in[6];
    const float* bih1 = (const float*)d_in[7];
    const float* bhh1 = (const float*)d_in[8];
    const float* Wfc  = (const float*)d_in[9];
    const float* bfc  = (const float*)d_in[10];
    float* out = (float*)d_out;

    dim3 grid(4096 / MT), block(NTHR);
    lstm_mfma16<<<grid, block, 0, stream>>>(x, Wih0, Whh0, bih0, bhh0,
                                            Wih1, Whh1, bih1, bhh1,
                                            Wfc, bfc, out);
}

// Round 9
// 348.177 us; speedup vs baseline: 1.0033x; 1.0033x over previous
//
#include <hip/hip_runtime.h>

// StockLSTM R21b = R21 resubmission (R8 bench died to infra: "container
//  failed twice" -- no kernel signal; kernel renamed to dodge any stale
//  cache). The experiment this round finally runs:
//  amdgpu_waves_per_eu(2,4). R18/R19/R20 occupancy trail (22%/19%/23% =
//  always 8 waves/CU = the MIN value) shows waves_per_eu min-only acts as
//  an occupancy CAP ((min) == (min,min)). (2,4): min 2 keeps the 256-reg
//  allocator budget R20 proved spill-free (VGPR=72); max 4 allows 4
//  waves/EU = 16 waves/CU = exactly TWO 8-wave blocks per CU (512 blocks /
//  256 CU = 2.0, uniform). Block A's transcendental back-phase overlaps
//  block B's post-barrier LDS/MFMA front-phase -- the ~760cy/step serial
//  overhead both phases share.
//  Work/CU at 2 blocks: VALU = R13's, LDS reads = R13's, MFMA = 2x R13
//  (dup cols; pipe was at 24%).
//  SENTINELS: Occupancy ~45-50% (cap theory), VGPR 72 / WRITE ~400 KB
//  (no spill), absmax bit-identical. dur <200 confirms overlap; ~300 at
//  50% occ = time-slicing -> abandon multi-block, pivot to trans algebra.

#define TT   256
#define II   5
#define HH   64
#define OO   25
#define MT   8
#define NTHR 512
#define XP   520        // x chunk row stride (ushorts): 64*8 + 8 skew
#define HSZ  512        // h parity block: [j>>3][b8][j&7] = 512 shorts
#define HF   65

typedef __attribute__((ext_vector_type(8))) short  short8;
typedef __attribute__((ext_vector_type(4))) float  floatx4;

#define MFMA(a, b, c) __builtin_amdgcn_mfma_f32_16x16x32_bf16(a, b, c, 0, 0, 0)

__device__ __forceinline__ float frcp(float x) { return __builtin_amdgcn_rcpf(x); }
__device__ __forceinline__ float fexp2(float x) { return __builtin_amdgcn_exp2f(x); }
__device__ __forceinline__ unsigned short bf16_rne(float f) {
    unsigned int u = __builtin_bit_cast(unsigned int, f);
    u += 0x7FFFu + ((u >> 16) & 1u);
    return (unsigned short)(u >> 16);
}
// gates arrive PRE-SCALED: g0,g1,g3 = -log2e*z ; g2 = +2log2e*z
__device__ __forceinline__ float cell_update(const floatx4& g, float& c) {
    const float gi = frcp(1.f + fexp2(g[0]));
    const float gf = frcp(1.f + fexp2(g[1]));
    const float gz = fmaf(-2.f, frcp(1.f + fexp2(g[2])), 1.f);
    const float go = frcp(1.f + fexp2(g[3]));
    c = fmaf(gf, c, gi * gz);
    const float tc = fmaf(-2.f, frcp(1.f + fexp2(c * 2.885390082f)), 1.f);
    return go * tc;
}

__global__ __attribute__((amdgpu_flat_work_group_size(512, 512),
                          amdgpu_waves_per_eu(2, 4)))
void lstm_mfma17b(const float* __restrict__ x,
                  const float* __restrict__ Wih0, const float* __restrict__ Whh0,
                  const float* __restrict__ bih0, const float* __restrict__ bhh0,
                  const float* __restrict__ Wih1, const float* __restrict__ Whh1,
                  const float* __restrict__ bih1, const float* __restrict__ bhh1,
                  const float* __restrict__ Wfc,  const float* __restrict__ bfc,
                  float* __restrict__ out)
{
    __shared__ __align__(16) unsigned short xhi[MT * XP];     // 8.3 KB
    __shared__ __align__(16) unsigned short h1hi[2 * HSZ];    // 2 KB
    __shared__ __align__(16) unsigned short h2hi[2 * HSZ];    // 2 KB
    __shared__ __align__(16) float          h2f[MT * HF];     // 2.1 KB

    const int tid   = threadIdx.x;
    const int w     = tid >> 6;          // wave 0..7: owns tiles 2w, 2w+1
    const int lane  = tid & 63;
    const int b8    = lane & 7;          // batch col (8 real; cols 8-15 dup)
    const int q     = lane >> 4;         // C row-quad / unit offset in tile
    const bool isl2 = ((lane >> 3) & 1) != 0;  // 0: own L1 cells, 1: own L2
    // lane's units: j_s = 8w + 4s + q (s=0,1). h layout [j>>3][b8][j&7]:
    const int hw_base = w * 64 + b8 * 8 + q;   // + 4*s
    const int ro8     = (q * 8 + b8) * 8;      // B-frag read (b8/b8+8 bcast)

    // ---------------- weights (bf16), nonlinearity scale folded in ----------------
    short8 A1h[2][2];   // [tile][k-chunk] Whh0
    short8 A2h[2][4];   // [tile][k-chunk] 0,1: Wih1 (h1); 2,3: Whh1 (h2)
    short8 Axwh[2];     // [tile] Wih0: k<II valid, rest exact zero
    {
        const int rr = lane & 15;
        const float sc = ((rr & 3) == 2) ? 2.885390082f : -1.442695041f;
        #pragma unroll
        for (int s = 0; s < 2; ++s) {
            const int g = (rr & 3) * 64 + 8 * w + 4 * s + (rr >> 2);
            #pragma unroll
            for (int c = 0; c < 2; ++c)
                #pragma unroll
                for (int jj = 0; jj < 8; ++jj)
                    A1h[s][c][jj] = (short)bf16_rne(sc * Whh0[g * HH + c * 32 + q * 8 + jj]);
            #pragma unroll
            for (int c = 0; c < 4; ++c)
                #pragma unroll
                for (int jj = 0; jj < 8; ++jj) {
                    const int k = c * 32 + q * 8 + jj;
                    float wv = (k < HH) ? Wih1[g * HH + k] : Whh1[g * HH + (k - HH)];
                    A2h[s][c][jj] = (short)bf16_rne(sc * wv);
                }
            #pragma unroll
            for (int jj = 0; jj < 8; ++jj) {
                const int k = q * 8 + jj;
                Axwh[s][jj] = (k < II) ? (short)bf16_rne(sc * Wih0[g * II + k]) : (short)0;
            }
        }
    }
    // per-lane bias for the layer THIS lane owns (post-added): 8 regs
    float biasm[2][4];
    #pragma unroll
    for (int s = 0; s < 2; ++s) {
        const int jj = 8 * w + 4 * s + q;
        #pragma unroll
        for (int r = 0; r < 4; ++r) {
            const int g = r * 64 + jj;
            const float sc = (r == 2) ? 2.885390082f : -1.442695041f;
            biasm[s][r] = isl2 ? sc * (bih1[g] + bhh1[g])
                               : sc * (bih0[g] + bhh0[g]);
        }
    }

    // ---------------- zero LDS ----------------
    for (int i = tid; i < MT * XP / 2; i += NTHR)
        ((unsigned int*)xhi)[i] = 0u;
    if (tid < HSZ) {                             // HSZ uints = 2*HSZ shorts
        ((unsigned int*)h1hi)[tid] = 0u;
        ((unsigned int*)h2hi)[tid] = 0u;
    }
    float cs0 = 0.f, cs1 = 0.f;                  // lane's 2 cell states
    __syncthreads();

    const int blockBase = blockIdx.x * MT;

    auto refill_x = [&](int t0) {
        const int rb = tid >> 6, dt = tid & 63;  // 8 rows x 64 t = 512 thr
        const float* src = x + ((size_t)(blockBase + rb) * TT + t0 + dt) * II;
        unsigned short* ph = xhi + rb * XP + dt * 8;
        #pragma unroll
        for (int ii = 0; ii < II; ++ii)
            ph[ii] = bf16_rne(src[ii]);
    };

    // per-lane h write pointers (parity + layer baked in; +4 for tile s=1):
    //  even intervals (WP=0,RP=1): sel0 writes h1[1], sel1 writes h2[0]
    //  odd  intervals (WP=1,RP=0): sel0 writes h1[0], sel1 writes h2[1]
    unsigned short* const hpE = (isl2 ? h2hi + 0 * HSZ : h1hi + 1 * HSZ) + hw_base;
    unsigned short* const hpO = (isl2 ? h2hi + 1 * HSZ : h1hi + 0 * HSZ) + hw_base;

    // ================= prologue: L1(0) =================
    refill_x(0);
    __syncthreads();
    {
        short8 Bxh = *(const short8*)(xhi + b8 * XP);       // dt = 0
        const floatx4 z4 = {0.f, 0.f, 0.f, 0.f};
        floatx4 a1t0 = MFMA(Axwh[0], Bxh, z4);
        floatx4 a1t1 = MFMA(Axwh[1], Bxh, z4);
        if (!isl2) {
            floatx4 g0, g1;
            #pragma unroll
            for (int r = 0; r < 4; ++r) { g0[r] = a1t0[r] + biasm[0][r];
                                          g1[r] = a1t1[r] + biasm[1][r]; }
            const float h0 = cell_update(g0, cs0);
            h1hi[0 * HSZ + hw_base + 0] = bf16_rne(h0);     // parity 0, s=0
            const float h1v = cell_update(g1, cs1);
            h1hi[0 * HSZ + hw_base + 4] = bf16_rne(h1v);    // parity 0, s=1
        }
    }
    __syncthreads();

    // x read pointer: STEP(i) reads dt=(i+1)&63; starts at dt=1.
    const unsigned short* xptr = xhi + b8 * XP + 8;

    // ================= merged main loop, unrolled by 2 =================
    // 14 MFMA/wave (2 tiles), then each lane finishes its OWN layer's 2 cells.
#define STEP_BODY(WP, RP, HP)                                                 \
    {                                                                         \
        short8 H1h0 = *(const short8*)(h1hi + (WP) * HSZ + ro8);              \
        short8 H1h1 = *(const short8*)(h1hi + (WP) * HSZ + 256 + ro8);        \
        short8 H2h0 = *(const short8*)(h2hi + (RP) * HSZ + ro8);              \
        short8 H2h1 = *(const short8*)(h2hi + (RP) * HSZ + 256 + ro8);        \
        short8 Bxh  = *(const short8*)(xptr);                                 \
        xptr += 8;                                                            \
        const floatx4 z4 = {0.f, 0.f, 0.f, 0.f};                              \
        floatx4 a2t0 = MFMA(A2h[0][0], H1h0, z4);                             \
        floatx4 a2t1 = MFMA(A2h[1][0], H1h0, z4);                             \
        a2t0 = MFMA(A2h[0][1], H1h1, a2t0);                                   \
        a2t1 = MFMA(A2h[1][1], H1h1, a2t1);                                   \
        a2t0 = MFMA(A2h[0][2], H2h0, a2t0);                                   \
        a2t1 = MFMA(A2h[1][2], H2h0, a2t1);                                   \
        a2t0 = MFMA(A2h[0][3], H2h1, a2t0);                                   \
        a2t1 = MFMA(A2h[1][3], H2h1, a2t1);                                   \
        floatx4 a1t0 = MFMA(Axwh[0], Bxh, z4);                                \
        floatx4 a1t1 = MFMA(Axwh[1], Bxh, z4);                                \
        a1t0 = MFMA(A1h[0][0], H1h0, a1t0);                                   \
        a1t1 = MFMA(A1h[1][0], H1h0, a1t1);                                   \
        a1t0 = MFMA(A1h[0][1], H1h1, a1t0);                                   \
        a1t1 = MFMA(A1h[1][1], H1h1, a1t1);                                   \
        floatx4 g0, g1;                                                       \
        _Pragma("unroll")                                                     \
        for (int r = 0; r < 4; ++r) {                                         \
            g0[r] = (isl2 ? a2t0[r] : a1t0[r]) + biasm[0][r];                 \
            g1[r] = (isl2 ? a2t1[r] : a1t1[r]) + biasm[1][r];                 \
        }                                                                     \
        {                                                                     \
            const float h = cell_update(g0, cs0);                             \
            (HP)[0] = bf16_rne(h);                                            \
        }                                                                     \
        {                                                                     \
            const float h = cell_update(g1, cs1);                             \
            (HP)[4] = bf16_rne(h);                                            \
        }                                                                     \
        __syncthreads();                                                      \
    }

    for (int i = 0; i < 254; i += 2) {
        STEP_BODY(0, 1, hpE)                 // interval i   (even)
        if (((i + 2) & 63) == 0) {           // refill before interval i+1
            refill_x(i + 2);
            xptr = xhi + b8 * XP;            //   next read is dt = 0
            __syncthreads();
        }
        STEP_BODY(1, 0, hpO)                 // interval i+1 (odd)
    }
    STEP_BODY(0, 1, hpE)                     // interval 254
#undef STEP_BODY

    // ================= epilogue: L2(255) =================
    {
        const floatx4 z4 = {0.f, 0.f, 0.f, 0.f};
        short8 H1h0 = *(const short8*)(h1hi + 1 * HSZ + ro8);
        short8 H1h1 = *(const short8*)(h1hi + 1 * HSZ + 256 + ro8);
        short8 H2h0 = *(const short8*)(h2hi + 0 * HSZ + ro8);
        short8 H2h1 = *(const short8*)(h2hi + 0 * HSZ + 256 + ro8);
        floatx4 a2t0 = MFMA(A2h[0][0], H1h0, z4);
        floatx4 a2t1 = MFMA(A2h[1][0], H1h0, z4);
        a2t0 = MFMA(A2h[0][1], H1h1, a2t0);
        a2t1 = MFMA(A2h[1][1], H1h1, a2t1);
        a2t0 = MFMA(A2h[0][2], H2h0, a2t0);
        a2t1 = MFMA(A2h[1][2], H2h0, a2t1);
        a2t0 = MFMA(A2h[0][3], H2h1, a2t0);
        a2t1 = MFMA(A2h[1][3], H2h1, a2t1);
        if (isl2) {
            floatx4 g0, g1;
            #pragma unroll
            for (int r = 0; r < 4; ++r) { g0[r] = a2t0[r] + biasm[0][r];
                                          g1[r] = a2t1[r] + biasm[1][r]; }
            const float h0 = cell_update(g0, cs0);
            h2f[b8 * HF + 8 * w + q] = h0;
            const float h1v = cell_update(g1, cs1);
            h2f[b8 * HF + 8 * w + 4 + q] = h1v;
        }
    }
    __syncthreads();

    // ================= FC epilogue =================
    if (tid < MT * OO) {
        const int bb = tid / OO, o = tid - bb * OO;
        float acc = bfc[o];
        const float* wr = Wfc + o * HH;
        const float* hr = h2f + bb * HF;
        #pragma unroll
        for (int j = 0; j < HH; ++j) acc += wr[j] * hr[j];
        out[((size_t)blockIdx.x * MT + bb) * OO + o] = acc;
    }
}

extern "C" void kernel_launch(void* const* d_in, const int* in_sizes, int n_in,
                              void* d_out, int out_size, void* d_ws, size_t ws_size,
                              hipStream_t stream) {
    const float* x    = (const float*)d_in[0];
    const float* Wih0 = (const float*)d_in[1];
    const float* Whh0 = (const float*)d_in[2];
    const float* bih0 = (const float*)d_in[3];
    const float* bhh0 = (const float*)d_in[4];
    const float* Wih1 = (const float*)d_in[5];
    const float* Whh1 = (const float*)d_in[6];
    const float* bih1 = (const float*)d_in[7];
    const float* bhh1 = (const float*)d_in[8];
    const float* Wfc  = (const float*)d_in[9];
    const float* bfc  = (const float*)d_in[10];
    float* out = (float*)d_out;

    dim3 grid(4096 / MT), block(NTHR);
    lstm_mfma17b<<<grid, block, 0, stream>>>(x, Wih0, Whh0, bih0, bhh0,
                                             Wih1, Whh1, bih1, bhh1,
                                             Wfc, bfc, out);
}